// Round 10
// baseline (599.936 us; speedup 1.0000x reference)
//
#include <hip/hip_runtime.h>
#include <hip/hip_bf16.h>
#include <stdint.h>
#include <math.h>

// TreeLSTM on MI355X — v17: re-establish v12b hot kernel + dispatch trims.
// v16 post-mortem: s_setprio pairs inside the fully-unrolled K-loop act as
// scheduler fences -> live-range blowup -> per-iteration scratch spill
// (WRITE 33->233MB, dur 91->150us). REVERTED: level_kernel is byte-exact
// v12b (verified 91us lev9 / 415.7us total). Kept safe wins:
//  (1) prep fused (xg + BtP pack + score-init)      -> -1 dispatch
//  (2) level1_kernel clone does lev1 + rh + atomic scores -> -1 dispatch
// 13 -> 11 dispatches; ~15us gap each.

typedef __bf16 bf16x8 __attribute__((ext_vector_type(8)));
typedef float  f32x4  __attribute__((ext_vector_type(4)));
typedef int    i32x4  __attribute__((ext_vector_type(4)));

__device__ __forceinline__ float sigf(float x) { return 1.f / (1.f + __expf(-x)); }
__device__ __forceinline__ float tanhfast(float x) {
    return 1.f - 2.f / (__expf(2.f * x) + 1.f);   // stable at |x| large
}

// blocks 0..255: xg4[(v*256+k)*4+g] = bW[g][k] + sum_i emb[v][i]*W[g][i][k]
// blocks 256..575: pack U into MFMA-fragment order BtP
// block  576     : out[0:192) = bs broadcast (score accumulator init)
__global__ void prep_kernel(const float* __restrict__ emb, const float* __restrict__ W,
                            const float* __restrict__ bW, const float* __restrict__ U,
                            const float* __restrict__ bs, float* __restrict__ xg4,
                            __bf16* __restrict__ BtP, float* __restrict__ out) {
    if (blockIdx.x < 256) {
        int g = blockIdx.x >> 6, v = blockIdx.x & 63, k = threadIdx.x;
        __shared__ float e[256];
        e[k] = emb[v * 256 + k];
        __syncthreads();
        float s = bW[g * 256 + k];
        const float* Wg = W + g * 65536 + k;
#pragma unroll 4
        for (int i = 0; i < 256; i++) s += e[i] * Wg[i * 256];
        xg4[(v * 256 + k) * 4 + g] = s;
    } else if (blockIdx.x < 576) {
        int t = (blockIdx.x - 256) * 256 + threadIdx.x;   // < 81920
        int g    = t >> 14;
        int r    = t & 16383;
        int ct   = r >> 10;
        int ks   = (r >> 6) & 15;
        int lane = t & 63;
        int lr = lane & 15, q = lane >> 4;
        int col = ct * 16 + lr;
        int kbase = ks * 32 + q * 8;
        bf16x8 v8;
#pragma unroll
        for (int e2 = 0; e2 < 8; e2++) {
            int k = kbase + e2;
            int s = k >> 8, kk = k & 255;
            v8[e2] = (__bf16)U[((g * 2 + s) * 256 + kk) * 256 + col];
        }
        *(bf16x8*)(BtP + (long)t * 8) = v8;
    } else {
        int t = threadIdx.x;
        if (t < 192) out[t] = bs[t % 3];
    }
}

__global__ void leaf_kernel(const int* __restrict__ ids, const float* __restrict__ xg4,
                            __bf16* __restrict__ h, __bf16* __restrict__ c) {
    int col = threadIdx.x;                 // 0..255
    int r0 = blockIdx.x * 32;              // 2048 blocks x 32 rows
    for (int r = r0; r < r0 + 32; r++) {
        int b = r >> 10, j = r & 1023;
        int id = ids[b * 2046 + 1022 + j];
        f32x4 xv = *(const f32x4*)(xg4 + (id * 256 + col) * 4);
        float ig = sigf(xv.y);
        float og = sigf(xv.z);
        float ug = tanhfast(xv.w);
        float cv = ig * ug;
        float hv = og * tanhfast(cv);
        h[r * 256 + col] = (__bf16)hv;
        c[r * 256 + col] = (__bf16)cv;
    }
}

// ===== big levels (9..2): v12b measured kernel, byte-exact =====
__global__ __launch_bounds__(1024, 4) void level_kernel(
    const __bf16* __restrict__ A, const __bf16* __restrict__ Cprev,
    const __bf16* __restrict__ BtP, const float* __restrict__ xg4,
    const int* __restrict__ ids, __bf16* __restrict__ h_out,
    __bf16* __restrict__ c_out, float* __restrict__ rh_out,
    int lev, int M, int RG, int NB, int NB16) {
    __shared__ __bf16 Blds[5 * 16 * 512];     // 80 KB
    const int gid = blockIdx.x;
    int rgslot, ct;
    if (NB16) { rgslot = gid & 15; ct = gid >> 4; }   // XCD-affine: gid%8==rg%8
    else      { rgslot = gid % NB; ct = gid / NB; }
    const int tid  = threadIdx.x;
    const int wave = tid >> 6;
    const int lane = tid & 63;
    const int lr = lane & 15, q = lane >> 4;
    const int gcol = ct * 16 + lr;
    const int n = 1 << lev;

    // ---- Stage B-slice -> LDS ONCE per block (fragment order, 16B/lane). ----
#pragma unroll
    for (int i = 0; i < 5; i++) {
        int cc = tid + i * 1024;
        int g = cc >> 10;
        int r = cc & 1023;
        *(i32x4*)(&Blds[g * 8192 + r * 8]) =
            *(const i32x4*)(BtP + (long)(g * 16 + ct) * 8192 + r * 8);
    }
    __syncthreads();

    // ---- First rg: prologue A prefetch into slots 0,1. ----
    int rg0 = rgslot;
    long wrow = (long)rg0 * 512 + wave * 32;
    const __bf16* Ap = A + (wrow + lr) * 512 + q * 8;   // + mt*8192 + s*32
    bf16x8 af[4][2];
    if (wrow < M) {
#pragma unroll
        for (int mt = 0; mt < 2; mt++) {
            af[0][mt] = *(const bf16x8*)(Ap + mt * 8192);
            af[1][mt] = *(const bf16x8*)(Ap + mt * 8192 + 32);
        }
    }

    for (int rg = rg0; rg < RG; rg += NB) {
        wrow = (long)rg * 512 + wave * 32;
        const bool active = (wrow < M);

        // Next rg's A base (wrap to current on last rg -> harmless re-reads).
        int rgn = rg + NB;
        long wrown = (rgn < RG) ? ((long)rgn * 512 + wave * 32) : wrow;
        const __bf16* Apn = A + (wrown + lr) * 512 + q * 8;

        // ---- Preload ids + children's c (latency hides under the K-loop). --
        int idv[2][4];
        __bf16 clv[2][4], crv[2][4];
        if (active) {
#pragma unroll
            for (int mt = 0; mt < 2; mt++)
#pragma unroll
                for (int v = 0; v < 4; v++) {
                    long grow = wrow + mt * 16 + q * 4 + v;
                    int b = (int)(grow >> lev);
                    int j = (int)(grow & (n - 1));
                    idv[mt][v] = ids[b * 2046 + (n - 2) + j];
                    clv[mt][v] = Cprev[grow * 512 + gcol];
                    crv[mt][v] = Cprev[grow * 512 + 256 + gcol];
                }
        }

        if (active) {
            f32x4 acc[5][2];
#pragma unroll
            for (int g2 = 0; g2 < 5; g2++)
#pragma unroll
                for (int mt = 0; mt < 2; mt++)
                    acc[g2][mt] = (f32x4){0.f, 0.f, 0.f, 0.f};

            bf16x8 bb[2][5];
#pragma unroll
            for (int g2 = 0; g2 < 5; g2++)
                bb[0][g2] = *(const bf16x8*)(&Blds[g2 * 8192 + lane * 8]);

#pragma unroll
            for (int s = 0; s < 16; s++) {
                {   // A: 2 ahead; wraps into NEXT rg's steps 0,1 at s=14,15.
                    int sp = s + 2;
                    const __bf16* P = (sp < 16) ? Ap : Apn;
                    int so = sp & 15;
#pragma unroll
                    for (int mt = 0; mt < 2; mt++)
                        af[sp & 3][mt] = *(const bf16x8*)(P + mt * 8192 + so * 32);
                }
                if (s + 1 < 16) {                  // B: 1 step ahead from LDS
#pragma unroll
                    for (int g2 = 0; g2 < 5; g2++)
                        bb[(s + 1) & 1][g2] =
                            *(const bf16x8*)(&Blds[g2 * 8192 + (s + 1) * 512 + lane * 8]);
                }
#pragma unroll
                for (int g2 = 0; g2 < 5; g2++)
#pragma unroll
                    for (int mt = 0; mt < 2; mt++)
                        acc[g2][mt] = __builtin_amdgcn_mfma_f32_16x16x32_bf16(
                            af[s & 3][mt], bb[s & 1][g2], acc[g2][mt], 0, 0, 0);
            }

            // ---- Epilogue: gate combine. col=lane&15, row=q*4+v. ----
#pragma unroll
            for (int mt = 0; mt < 2; mt++) {
#pragma unroll
                for (int v = 0; v < 4; v++) {
                    long grow = wrow + mt * 16 + q * 4 + v;
                    f32x4 xv = *(const f32x4*)(xg4 + (idv[mt][v] * 256 + gcol) * 4);
                    float fl = sigf(acc[0][mt][v] + xv.x);   // f_l,f_r share gate0
                    float fr = sigf(acc[1][mt][v] + xv.x);
                    float ig = sigf(acc[2][mt][v] + xv.y);
                    float og = sigf(acc[3][mt][v] + xv.z);
                    float ug = tanhfast(acc[4][mt][v] + xv.w);
                    float cv = ig * ug + fl * (float)clv[mt][v]
                                       + fr * (float)crv[mt][v];
                    float hv = og * tanhfast(cv);
                    h_out[grow * 256 + gcol] = (__bf16)hv;
                    c_out[grow * 256 + gcol] = (__bf16)cv;
                    if (rh_out) rh_out[grow * 256 + gcol] = hv;
                }
            }
        }
        Ap = Apn;
    }
}

// ===== lev 1 + rh + scores: clone of the v12b body specialized to lev=1.
// 16 blocks (one per ct), M=128 -> waves 0..3 active. Writes rh to out+192
// and atomically accumulates scores into out[0:192) (init'd to bs by prep).
__global__ __launch_bounds__(1024, 4) void level1_kernel(
    const __bf16* __restrict__ A, const __bf16* __restrict__ Cprev,
    const __bf16* __restrict__ BtP, const float* __restrict__ xg4,
    const int* __restrict__ ids, const float* __restrict__ Ws,
    float* __restrict__ out) {
    __shared__ __bf16 Blds[5 * 16 * 512];     // 80 KB
    const int ct   = blockIdx.x;              // 0..15
    const int tid  = threadIdx.x;
    const int wave = tid >> 6;
    const int lane = tid & 63;
    const int lr = lane & 15, q = lane >> 4;
    const int gcol = ct * 16 + lr;

#pragma unroll
    for (int i = 0; i < 5; i++) {
        int cc = tid + i * 1024;
        int g = cc >> 10;
        int r = cc & 1023;
        *(i32x4*)(&Blds[g * 8192 + r * 8]) =
            *(const i32x4*)(BtP + (long)(g * 16 + ct) * 8192 + r * 8);
    }
    __syncthreads();

    long wrow = (long)wave * 32;
    if (wrow >= 128) return;
    const __bf16* Ap = A + (wrow + lr) * 512 + q * 8;

    bf16x8 af[4][2];
#pragma unroll
    for (int mt = 0; mt < 2; mt++) {
        af[0][mt] = *(const bf16x8*)(Ap + mt * 8192);
        af[1][mt] = *(const bf16x8*)(Ap + mt * 8192 + 32);
    }

    int idv[2][4];
    __bf16 clv[2][4], crv[2][4];
#pragma unroll
    for (int mt = 0; mt < 2; mt++)
#pragma unroll
        for (int v = 0; v < 4; v++) {
            long grow = wrow + mt * 16 + q * 4 + v;
            int b = (int)(grow >> 1);
            int j = (int)(grow & 1);
            idv[mt][v] = ids[b * 2046 + j];          // off = n-2 = 0
            clv[mt][v] = Cprev[grow * 512 + gcol];
            crv[mt][v] = Cprev[grow * 512 + 256 + gcol];
        }

    f32x4 acc[5][2];
#pragma unroll
    for (int g2 = 0; g2 < 5; g2++)
#pragma unroll
        for (int mt = 0; mt < 2; mt++) acc[g2][mt] = (f32x4){0.f, 0.f, 0.f, 0.f};

    bf16x8 bb[2][5];
#pragma unroll
    for (int g2 = 0; g2 < 5; g2++)
        bb[0][g2] = *(const bf16x8*)(&Blds[g2 * 8192 + lane * 8]);

#pragma unroll
    for (int s = 0; s < 16; s++) {
        {   // A: 2 ahead, wrap to own steps 0,1 (harmless re-reads).
            int sp = s + 2;
            int so = sp & 15;
#pragma unroll
            for (int mt = 0; mt < 2; mt++)
                af[sp & 3][mt] = *(const bf16x8*)(Ap + mt * 8192 + so * 32);
        }
        if (s + 1 < 16) {
#pragma unroll
            for (int g2 = 0; g2 < 5; g2++)
                bb[(s + 1) & 1][g2] =
                    *(const bf16x8*)(&Blds[g2 * 8192 + (s + 1) * 512 + lane * 8]);
        }
#pragma unroll
        for (int g2 = 0; g2 < 5; g2++)
#pragma unroll
            for (int mt = 0; mt < 2; mt++)
                acc[g2][mt] = __builtin_amdgcn_mfma_f32_16x16x32_bf16(
                    af[s & 3][mt], bb[s & 1][g2], acc[g2][mt], 0, 0, 0);
    }

#pragma unroll
    for (int mt = 0; mt < 2; mt++) {
#pragma unroll
        for (int v = 0; v < 4; v++) {
            long grow = wrow + mt * 16 + q * 4 + v;
            int b = (int)(grow >> 1);
            int j = (int)(grow & 1);
            f32x4 xv = *(const f32x4*)(xg4 + (idv[mt][v] * 256 + gcol) * 4);
            float fl = sigf(acc[0][mt][v] + xv.x);
            float fr = sigf(acc[1][mt][v] + xv.x);
            float ig = sigf(acc[2][mt][v] + xv.y);
            float og = sigf(acc[3][mt][v] + xv.z);
            float ug = tanhfast(acc[4][mt][v] + xv.w);
            float cv = ig * ug + fl * (float)clv[mt][v] + fr * (float)crv[mt][v];
            float hv = og * tanhfast(cv);
            out[192 + grow * 256 + gcol] = hv;        // rh (b*512 + j*256 + col)
            const float* wrow3 = Ws + (j * 256 + gcol) * 3;
#pragma unroll
            for (int t = 0; t < 3; t++)
                atomicAdd(&out[b * 3 + t], hv * wrow3[t]);
        }
    }
}

extern "C" void kernel_launch(void* const* d_in, const int* in_sizes, int n_in,
                              void* d_out, int out_size, void* d_ws, size_t ws_size,
                              hipStream_t stream) {
    const int*   ids = (const int*)  d_in[0];
    const float* emb = (const float*)d_in[1];
    const float* W   = (const float*)d_in[2];
    const float* bW  = (const float*)d_in[3];
    const float* U   = (const float*)d_in[4];
    const float* Ws  = (const float*)d_in[5];
    const float* bs  = (const float*)d_in[6];
    float* out = (float*)d_out;   // [0:192) scores, [192:) root_hidden (64x512)

    char* ws = (char*)d_ws;
    float*  xg4 = (float*)ws;                   //   262144 B : xg4[64][256][4]
    __bf16* BtP = (__bf16*)(ws + 262144);       //  1310720 B : packed B fragments
    __bf16* h0  = (__bf16*)(ws + 1572864);      // 33554432 B : h ping (leaf-sized)
    __bf16* c0  = (__bf16*)(ws + 35127296);     // 33554432 B
    __bf16* h1  = (__bf16*)(ws + 68681728);     // 16777216 B : h pong
    __bf16* c1  = (__bf16*)(ws + 85458944);     // 16777216 B   (total 102236160 B)

    prep_kernel<<<dim3(577), dim3(256), 0, stream>>>(emb, W, bW, U, bs, xg4, BtP, out);
    leaf_kernel<<<dim3(2048), dim3(256), 0, stream>>>(ids, xg4, h0, c0);

    __bf16* hb[2] = {h0, h1};
    __bf16* cb[2] = {c0, c1};
    int cur = 0;
    for (int lev = 9; lev >= 2; lev--) {
        int M = 64 << lev;                      // B * 2^lev rows
        int RG = M >> 9; if (RG < 1) RG = 1;
        int NB = (RG < 16) ? RG : 16;
        level_kernel<<<dim3(16 * NB), dim3(1024), 0, stream>>>(
            hb[cur], cb[cur], BtP, xg4, ids, hb[1 - cur], cb[1 - cur], nullptr,
            lev, M, RG, NB, (NB == 16) ? 1 : 0);
        cur = 1 - cur;
    }
    // lev 1 + rh + scores fused (scores accumulated atomically; init'd by prep)
    level1_kernel<<<dim3(16), dim3(1024), 0, stream>>>(
        hb[cur], cb[cur], BtP, xg4, ids, Ws, out);
}

// Round 11
// 457.466 us; speedup vs baseline: 1.3114x; 1.3114x over previous
//
#include <hip/hip_runtime.h>
#include <hip/hip_bf16.h>
#include <stdint.h>
#include <math.h>

// TreeLSTM on MI355X — v18: v12b verified hot path + fused tail.
// v17 post-mortem: atomic-scores fusion = 209us of serialized atomics (98k
// RMWs on 36 cachelines). REVERTED. Remaining lever: ~15us/launch gap x 13.
// v18: lev9..6 + leaf = byte-exact v12b kernels. prep fused (xg+BtP+cnt=0).
// tail_kernel fuses lev5..1 + rh + scores in ONE 32-block launch using a
// monotonic spin barrier (agent-scope release add / acquire load + fences;
// 32 blocks <= 256 CUs -> co-resident; counter zeroed by prep each launch).
// Counter sits past the 102MB layout, guarded by ws_size; else fall back to
// per-level launches (exact v12b tail). 13 dispatches -> 7 (or 12 fallback).

typedef __bf16 bf16x8 __attribute__((ext_vector_type(8)));
typedef float  f32x4  __attribute__((ext_vector_type(4)));
typedef int    i32x4  __attribute__((ext_vector_type(4)));

__device__ __forceinline__ float sigf(float x) { return 1.f / (1.f + __expf(-x)); }
__device__ __forceinline__ float tanhfast(float x) {
    return 1.f - 2.f / (__expf(2.f * x) + 1.f);   // stable at |x| large
}

// blocks 0..255: xg4; blocks 256..575: BtP pack; block 576: zero barrier cnt.
__global__ void prep_kernel(const float* __restrict__ emb, const float* __restrict__ W,
                            const float* __restrict__ bW, const float* __restrict__ U,
                            float* __restrict__ xg4, __bf16* __restrict__ BtP,
                            int* cnt) {
    if (blockIdx.x < 256) {
        int g = blockIdx.x >> 6, v = blockIdx.x & 63, k = threadIdx.x;
        __shared__ float e[256];
        e[k] = emb[v * 256 + k];
        __syncthreads();
        float s = bW[g * 256 + k];
        const float* Wg = W + g * 65536 + k;
#pragma unroll 4
        for (int i = 0; i < 256; i++) s += e[i] * Wg[i * 256];
        xg4[(v * 256 + k) * 4 + g] = s;
    } else if (blockIdx.x < 576) {
        int t = (blockIdx.x - 256) * 256 + threadIdx.x;   // < 81920
        int g    = t >> 14;
        int r    = t & 16383;
        int ct   = r >> 10;
        int ks   = (r >> 6) & 15;
        int lane = t & 63;
        int lr = lane & 15, q = lane >> 4;
        int col = ct * 16 + lr;
        int kbase = ks * 32 + q * 8;
        bf16x8 v8;
#pragma unroll
        for (int e2 = 0; e2 < 8; e2++) {
            int k = kbase + e2;
            int s = k >> 8, kk = k & 255;
            v8[e2] = (__bf16)U[((g * 2 + s) * 256 + kk) * 256 + col];
        }
        *(bf16x8*)(BtP + (long)t * 8) = v8;
    } else {
        if (threadIdx.x == 0 && cnt) *cnt = 0;
    }
}

__global__ void leaf_kernel(const int* __restrict__ ids, const float* __restrict__ xg4,
                            __bf16* __restrict__ h, __bf16* __restrict__ c) {
    int col = threadIdx.x;                 // 0..255
    int r0 = blockIdx.x * 32;              // 2048 blocks x 32 rows
    for (int r = r0; r < r0 + 32; r++) {
        int b = r >> 10, j = r & 1023;
        int id = ids[b * 2046 + 1022 + j];
        f32x4 xv = *(const f32x4*)(xg4 + (id * 256 + col) * 4);
        float ig = sigf(xv.y);
        float og = sigf(xv.z);
        float ug = tanhfast(xv.w);
        float cv = ig * ug;
        float hv = og * tanhfast(cv);
        h[r * 256 + col] = (__bf16)hv;
        c[r * 256 + col] = (__bf16)cv;
    }
}

// ===== big levels: v12b measured kernel, byte-exact =====
__global__ __launch_bounds__(1024, 4) void level_kernel(
    const __bf16* __restrict__ A, const __bf16* __restrict__ Cprev,
    const __bf16* __restrict__ BtP, const float* __restrict__ xg4,
    const int* __restrict__ ids, __bf16* __restrict__ h_out,
    __bf16* __restrict__ c_out, float* __restrict__ rh_out,
    int lev, int M, int RG, int NB, int NB16) {
    __shared__ __bf16 Blds[5 * 16 * 512];     // 80 KB
    const int gid = blockIdx.x;
    int rgslot, ct;
    if (NB16) { rgslot = gid & 15; ct = gid >> 4; }   // XCD-affine: gid%8==rg%8
    else      { rgslot = gid % NB; ct = gid / NB; }
    const int tid  = threadIdx.x;
    const int wave = tid >> 6;
    const int lane = tid & 63;
    const int lr = lane & 15, q = lane >> 4;
    const int gcol = ct * 16 + lr;
    const int n = 1 << lev;

#pragma unroll
    for (int i = 0; i < 5; i++) {
        int cc = tid + i * 1024;
        int g = cc >> 10;
        int r = cc & 1023;
        *(i32x4*)(&Blds[g * 8192 + r * 8]) =
            *(const i32x4*)(BtP + (long)(g * 16 + ct) * 8192 + r * 8);
    }
    __syncthreads();

    int rg0 = rgslot;
    long wrow = (long)rg0 * 512 + wave * 32;
    const __bf16* Ap = A + (wrow + lr) * 512 + q * 8;   // + mt*8192 + s*32
    bf16x8 af[4][2];
    if (wrow < M) {
#pragma unroll
        for (int mt = 0; mt < 2; mt++) {
            af[0][mt] = *(const bf16x8*)(Ap + mt * 8192);
            af[1][mt] = *(const bf16x8*)(Ap + mt * 8192 + 32);
        }
    }

    for (int rg = rg0; rg < RG; rg += NB) {
        wrow = (long)rg * 512 + wave * 32;
        const bool active = (wrow < M);

        int rgn = rg + NB;
        long wrown = (rgn < RG) ? ((long)rgn * 512 + wave * 32) : wrow;
        const __bf16* Apn = A + (wrown + lr) * 512 + q * 8;

        int idv[2][4];
        __bf16 clv[2][4], crv[2][4];
        if (active) {
#pragma unroll
            for (int mt = 0; mt < 2; mt++)
#pragma unroll
                for (int v = 0; v < 4; v++) {
                    long grow = wrow + mt * 16 + q * 4 + v;
                    int b = (int)(grow >> lev);
                    int j = (int)(grow & (n - 1));
                    idv[mt][v] = ids[b * 2046 + (n - 2) + j];
                    clv[mt][v] = Cprev[grow * 512 + gcol];
                    crv[mt][v] = Cprev[grow * 512 + 256 + gcol];
                }
        }

        if (active) {
            f32x4 acc[5][2];
#pragma unroll
            for (int g2 = 0; g2 < 5; g2++)
#pragma unroll
                for (int mt = 0; mt < 2; mt++)
                    acc[g2][mt] = (f32x4){0.f, 0.f, 0.f, 0.f};

            bf16x8 bb[2][5];
#pragma unroll
            for (int g2 = 0; g2 < 5; g2++)
                bb[0][g2] = *(const bf16x8*)(&Blds[g2 * 8192 + lane * 8]);

#pragma unroll
            for (int s = 0; s < 16; s++) {
                {   // A: 2 ahead; wraps into NEXT rg's steps 0,1 at s=14,15.
                    int sp = s + 2;
                    const __bf16* P = (sp < 16) ? Ap : Apn;
                    int so = sp & 15;
#pragma unroll
                    for (int mt = 0; mt < 2; mt++)
                        af[sp & 3][mt] = *(const bf16x8*)(P + mt * 8192 + so * 32);
                }
                if (s + 1 < 16) {                  // B: 1 step ahead from LDS
#pragma unroll
                    for (int g2 = 0; g2 < 5; g2++)
                        bb[(s + 1) & 1][g2] =
                            *(const bf16x8*)(&Blds[g2 * 8192 + (s + 1) * 512 + lane * 8]);
                }
#pragma unroll
                for (int g2 = 0; g2 < 5; g2++)
#pragma unroll
                    for (int mt = 0; mt < 2; mt++)
                        acc[g2][mt] = __builtin_amdgcn_mfma_f32_16x16x32_bf16(
                            af[s & 3][mt], bb[s & 1][g2], acc[g2][mt], 0, 0, 0);
            }

#pragma unroll
            for (int mt = 0; mt < 2; mt++) {
#pragma unroll
                for (int v = 0; v < 4; v++) {
                    long grow = wrow + mt * 16 + q * 4 + v;
                    f32x4 xv = *(const f32x4*)(xg4 + (idv[mt][v] * 256 + gcol) * 4);
                    float fl = sigf(acc[0][mt][v] + xv.x);   // f_l,f_r share gate0
                    float fr = sigf(acc[1][mt][v] + xv.x);
                    float ig = sigf(acc[2][mt][v] + xv.y);
                    float og = sigf(acc[3][mt][v] + xv.z);
                    float ug = tanhfast(acc[4][mt][v] + xv.w);
                    float cv = ig * ug + fl * (float)clv[mt][v]
                                       + fr * (float)crv[mt][v];
                    float hv = og * tanhfast(cv);
                    h_out[grow * 256 + gcol] = (__bf16)hv;
                    c_out[grow * 256 + gcol] = (__bf16)cv;
                    if (rh_out) rh_out[grow * 256 + gcol] = hv;
                }
            }
        }
        Ap = Apn;
    }
}

__global__ void scores_kernel(const float* __restrict__ rh, const float* __restrict__ Ws,
                              const float* __restrict__ bs, float* __restrict__ out) {
    int b = blockIdx.x;
    int t = threadIdx.x >> 6, lane = threadIdx.x & 63;
    float s = 0.f;
    for (int i = lane; i < 512; i += 64) s += rh[b * 512 + i] * Ws[i * 3 + t];
    for (int o = 32; o > 0; o >>= 1) s += __shfl_down(s, o);
    if (lane == 0) out[b * 3 + t] = s + bs[t];
}

// Monotonic spin barrier across the 32 co-resident tail blocks.
__device__ __forceinline__ void gbar(int* cnt, int target) {
    __syncthreads();
    if (threadIdx.x == 0) {
        __hip_atomic_fetch_add(cnt, 1, __ATOMIC_RELEASE, __HIP_MEMORY_SCOPE_AGENT);
        while (__hip_atomic_load(cnt, __ATOMIC_ACQUIRE,
                                 __HIP_MEMORY_SCOPE_AGENT) < target)
            __builtin_amdgcn_s_sleep(8);
    }
    __syncthreads();
    __threadfence();
}

// ===== tail: lev 5..1 + rh + scores, one launch, 32 blocks x 1024 thr. =====
// Block gid: ct = gid>>1, rgslot = gid&1; lev5 loops rg {rgslot, rgslot+2}.
__global__ __launch_bounds__(1024, 4) void tail_kernel(
    __bf16* __restrict__ hA, __bf16* __restrict__ cA,
    __bf16* __restrict__ hB, __bf16* __restrict__ cB,
    const __bf16* __restrict__ BtP, const float* __restrict__ xg4,
    const int* __restrict__ ids, const float* __restrict__ Ws,
    const float* __restrict__ bs, float* __restrict__ out, int* cnt) {
    __shared__ __bf16 Blds[5 * 16 * 512];     // 80 KB
    const int gid = blockIdx.x;               // 0..31
    const int rgslot = gid & 1;
    const int ct     = gid >> 1;
    const int tid  = threadIdx.x;
    const int wave = tid >> 6;
    const int lane = tid & 63;
    const int lr = lane & 15, q = lane >> 4;
    const int gcol = ct * 16 + lr;

#pragma unroll
    for (int i = 0; i < 5; i++) {
        int cc = tid + i * 1024;
        int g = cc >> 10;
        int r = cc & 1023;
        *(i32x4*)(&Blds[g * 8192 + r * 8]) =
            *(const i32x4*)(BtP + (long)(g * 16 + ct) * 8192 + r * 8);
    }
    __syncthreads();

    for (int lev = 5; lev >= 1; lev--) {
        const int k = 5 - lev;
        const __bf16* A  = (k & 1) ? hB : hA;
        const __bf16* Cp = (k & 1) ? cB : cA;
        __bf16* Ho = (k & 1) ? hA : hB;
        __bf16* Co = (k & 1) ? cA : cB;
        const int M  = 64 << lev;
        const int RG = (M + 511) >> 9;
        const int n  = 1 << lev;

        for (int rg = rgslot; rg < RG; rg += 2) {
            const long wrow = (long)rg * 512 + wave * 32;
            const bool active = (wrow < M);
            if (active) {
                const __bf16* Ap = A + (wrow + lr) * 512 + q * 8;

                int idv[2][4];
                __bf16 clv[2][4], crv[2][4];
#pragma unroll
                for (int mt = 0; mt < 2; mt++)
#pragma unroll
                    for (int v = 0; v < 4; v++) {
                        long grow = wrow + mt * 16 + q * 4 + v;
                        int b = (int)(grow >> lev);
                        int j = (int)(grow & (n - 1));
                        idv[mt][v] = ids[b * 2046 + (n - 2) + j];
                        clv[mt][v] = Cp[grow * 512 + gcol];
                        crv[mt][v] = Cp[grow * 512 + 256 + gcol];
                    }

                f32x4 acc[5][2];
#pragma unroll
                for (int g2 = 0; g2 < 5; g2++)
#pragma unroll
                    for (int mt = 0; mt < 2; mt++)
                        acc[g2][mt] = (f32x4){0.f, 0.f, 0.f, 0.f};

                bf16x8 af[4][2];
#pragma unroll
                for (int mt = 0; mt < 2; mt++) {
                    af[0][mt] = *(const bf16x8*)(Ap + mt * 8192);
                    af[1][mt] = *(const bf16x8*)(Ap + mt * 8192 + 32);
                }
                bf16x8 bb[2][5];
#pragma unroll
                for (int g2 = 0; g2 < 5; g2++)
                    bb[0][g2] = *(const bf16x8*)(&Blds[g2 * 8192 + lane * 8]);

#pragma unroll
                for (int s = 0; s < 16; s++) {
                    if (s + 2 < 16) {
#pragma unroll
                        for (int mt = 0; mt < 2; mt++)
                            af[(s + 2) & 3][mt] =
                                *(const bf16x8*)(Ap + mt * 8192 + (s + 2) * 32);
                    }
                    if (s + 1 < 16) {
#pragma unroll
                        for (int g2 = 0; g2 < 5; g2++)
                            bb[(s + 1) & 1][g2] = *(const bf16x8*)(
                                &Blds[g2 * 8192 + (s + 1) * 512 + lane * 8]);
                    }
#pragma unroll
                    for (int g2 = 0; g2 < 5; g2++)
#pragma unroll
                        for (int mt = 0; mt < 2; mt++)
                            acc[g2][mt] = __builtin_amdgcn_mfma_f32_16x16x32_bf16(
                                af[s & 3][mt], bb[s & 1][g2], acc[g2][mt], 0, 0, 0);
                }

#pragma unroll
                for (int mt = 0; mt < 2; mt++) {
#pragma unroll
                    for (int v = 0; v < 4; v++) {
                        long grow = wrow + mt * 16 + q * 4 + v;
                        f32x4 xv = *(const f32x4*)(xg4 + (idv[mt][v] * 256 + gcol) * 4);
                        float fl = sigf(acc[0][mt][v] + xv.x);
                        float fr = sigf(acc[1][mt][v] + xv.x);
                        float ig = sigf(acc[2][mt][v] + xv.y);
                        float og = sigf(acc[3][mt][v] + xv.z);
                        float ug = tanhfast(acc[4][mt][v] + xv.w);
                        float cv = ig * ug + fl * (float)clv[mt][v]
                                           + fr * (float)crv[mt][v];
                        float hv = og * tanhfast(cv);
                        Ho[grow * 256 + gcol] = (__bf16)hv;
                        Co[grow * 256 + gcol] = (__bf16)cv;
                        if (lev == 1) out[192 + grow * 256 + gcol] = hv;
                    }
                }
            }
        }
        gbar(cnt, 32 * (k + 1));   // level L visible everywhere before L-1
    }

    // ---- scores: each block does 2 batches from global rh. ----
#pragma unroll
    for (int bb2 = 0; bb2 < 2; bb2++) {
        int b = gid * 2 + bb2;
        if (tid < 192) {
            int t = tid >> 6, ln = tid & 63;
            float s = 0.f;
            for (int i = ln; i < 512; i += 64)
                s += out[192 + b * 512 + i] * Ws[i * 3 + t];
            for (int o = 32; o > 0; o >>= 1) s += __shfl_down(s, o);
            if (ln == 0) out[b * 3 + t] = s + bs[t];
        }
    }
}

extern "C" void kernel_launch(void* const* d_in, const int* in_sizes, int n_in,
                              void* d_out, int out_size, void* d_ws, size_t ws_size,
                              hipStream_t stream) {
    const int*   ids = (const int*)  d_in[0];
    const float* emb = (const float*)d_in[1];
    const float* W   = (const float*)d_in[2];
    const float* bW  = (const float*)d_in[3];
    const float* U   = (const float*)d_in[4];
    const float* Ws  = (const float*)d_in[5];
    const float* bs  = (const float*)d_in[6];
    float* out = (float*)d_out;   // [0:192) scores, [192:) root_hidden (64x512)

    char* ws = (char*)d_ws;
    float*  xg4 = (float*)ws;                   //   262144 B : xg4[64][256][4]
    __bf16* BtP = (__bf16*)(ws + 262144);       //  1310720 B : packed B fragments
    __bf16* h0  = (__bf16*)(ws + 1572864);      // 33554432 B : h ping (leaf-sized)
    __bf16* c0  = (__bf16*)(ws + 35127296);     // 33554432 B
    __bf16* h1  = (__bf16*)(ws + 68681728);     // 16777216 B : h pong
    __bf16* c1  = (__bf16*)(ws + 85458944);     // 16777216 B  (base total 102236160)
    const size_t CNT_OFF = 102236160;
    bool fused_tail = (ws_size >= CNT_OFF + 64);
    int* cnt = fused_tail ? (int*)(ws + CNT_OFF) : nullptr;

    prep_kernel<<<dim3(577), dim3(256), 0, stream>>>(emb, W, bW, U, xg4, BtP, cnt);
    leaf_kernel<<<dim3(2048), dim3(256), 0, stream>>>(ids, xg4, h0, c0);

    __bf16* hb[2] = {h0, h1};
    __bf16* cb[2] = {c0, c1};
    int cur = 0;
    int last_big = fused_tail ? 6 : 1;
    for (int lev = 9; lev >= last_big; lev--) {
        int M = 64 << lev;                      // B * 2^lev rows
        int RG = M >> 9; if (RG < 1) RG = 1;
        int NB = (RG < 16) ? RG : 16;
        float* rh = (!fused_tail && lev == 1) ? (out + 192) : nullptr;
        level_kernel<<<dim3(16 * NB), dim3(1024), 0, stream>>>(
            hb[cur], cb[cur], BtP, xg4, ids, hb[1 - cur], cb[1 - cur], rh,
            lev, M, RG, NB, (NB == 16) ? 1 : 0);
        cur = 1 - cur;
    }
    if (fused_tail) {
        // cur = index of lev6 output = tail input
        tail_kernel<<<dim3(32), dim3(1024), 0, stream>>>(
            hb[cur], cb[cur], hb[1 - cur], cb[1 - cur],
            BtP, xg4, ids, Ws, bs, out, cnt);
    } else {
        scores_kernel<<<dim3(64), dim3(192), 0, stream>>>(out + 192, Ws, bs, out);
    }
}